// Round 14
// baseline (100.197 us; speedup 1.0000x reference)
//
#include <hip/hip_runtime.h>
#include <math.h>

#define NEG_BIG -1.0e30f
#define BSHIFT 8                 // bucket = 256 target-node ids
#define MAXB 256

typedef __attribute__((ext_vector_type(8))) short short8v;   // 8 bf16
typedef __attribute__((ext_vector_type(4))) float f32x4;

__device__ __forceinline__ ushort f2bf(float f) {
  unsigned u = __float_as_uint(f);
  unsigned r = (u + 0x7fffu + ((u >> 16) & 1u)) >> 16;  // round-to-nearest-even
  return (ushort)r;
}
__device__ __forceinline__ float bf_lo(unsigned u) { return __uint_as_float(u << 16); }
__device__ __forceinline__ float bf_hi(unsigned u) { return __uint_as_float(u & 0xffff0000u); }

// ================= gemm body (device fn): 64 rows per block =================
// Wh = h @ W via MFMA bf16 (zero LDS) -> permuted-layout Whb + fused alpha.
// k-map (applied identically to A and B -> result layout-invariant): k = kk*32+lg*8+i
// Whb PERMUTED row layout: Whb[r][lm*8 + n0] holds true col (n0*16 + lm).
__device__ __forceinline__ void gemm_body(int gb, const float* __restrict__ h,
                                          const ushort* __restrict__ Wbf,
                                          const float* __restrict__ a,
                                          ushort* __restrict__ Whb,
                                          float* __restrict__ asrc,
                                          float* __restrict__ adst, int N) {
  int tid = (int)threadIdx.x;
  int w = tid >> 6;
  int l = tid & 63;
  int lg = l >> 4;
  int lm = l & 15;
  int r0 = gb * 64 + 16 * w;
  const short8v* Wb8 = (const short8v*)Wbf;

  float as_v[8], ad_v[8];
#pragma unroll
  for (int n0 = 0; n0 < 8; ++n0) {
    as_v[n0] = a[n0 * 16 + lm];
    ad_v[n0] = a[128 + n0 * 16 + lm];
  }

  f32x4 acc[8];
#pragma unroll
  for (int n0 = 0; n0 < 8; ++n0) acc[n0] = (f32x4){0.f, 0.f, 0.f, 0.f};

  int arow = r0 + lm;
  const float* hrow = h + (size_t)arow * 128;
  bool rok = (arow < N);

#pragma unroll
  for (int kk = 0; kk < 4; ++kk) {
    short8v av;
    if (rok) {
      const float4* hp = (const float4*)(hrow + kk * 32 + lg * 8);
      float4 x0 = hp[0], x1 = hp[1];
      av[0] = (short)f2bf(x0.x); av[1] = (short)f2bf(x0.y);
      av[2] = (short)f2bf(x0.z); av[3] = (short)f2bf(x0.w);
      av[4] = (short)f2bf(x1.x); av[5] = (short)f2bf(x1.y);
      av[6] = (short)f2bf(x1.z); av[7] = (short)f2bf(x1.w);
    } else {
      av = (short8v){0, 0, 0, 0, 0, 0, 0, 0};
    }
#pragma unroll
    for (int n0 = 0; n0 < 8; ++n0) {
      short8v bv = Wb8[(kk * 8 + n0) * 64 + l];
      acc[n0] = __builtin_amdgcn_mfma_f32_16x16x32_bf16(av, bv, acc[n0], 0, 0, 0);
    }
  }

#pragma unroll
  for (int reg = 0; reg < 4; ++reg) {
    int r = r0 + lg * 4 + reg;
    if (r < N) {
      short8v pk;
#pragma unroll
      for (int n0 = 0; n0 < 8; ++n0) pk[n0] = (short)f2bf(acc[n0][reg]);
      *(short8v*)(Whb + (size_t)r * 128 + lm * 8) = pk;
    }
  }

#pragma unroll
  for (int reg = 0; reg < 4; ++reg) {
    float ps = 0.f, pd = 0.f;
#pragma unroll
    for (int n0 = 0; n0 < 8; ++n0) {
      ps += acc[n0][reg] * as_v[n0];
      pd += acc[n0][reg] * ad_v[n0];
    }
#pragma unroll
    for (int off = 1; off < 16; off <<= 1) {
      ps += __shfl_xor(ps, off);
      pd += __shfl_xor(pd, off);
    }
    int r = r0 + lg * 4 + reg;
    if (lm == 0 && r < N) { asrc[r] = ps; adst[r] = pd; }
  }
}

// ---------- K1: W pack (bf16 MFMA B-fragment order) + zero bucket_count/done ----------
__global__ void wprep_k(const float* __restrict__ W, ushort* __restrict__ Wbf,
                        int* __restrict__ bucket_count, int* __restrict__ done) {
  int j = blockIdx.x * blockDim.x + threadIdx.x;
  if (j < MAXB) bucket_count[j] = 0;
  if (j == 0) *done = 0;
  if (j >= 128 * 128) return;
  int i = j & 7;
  int l = (j >> 3) & 63;
  int n0 = (j >> 9) & 7;
  int kk = j >> 12;
  int k = kk * 32 + ((l >> 4) & 3) * 8 + i;
  int n = n0 * 16 + (l & 15);
  Wbf[j] = f2bf(W[k * 128 + n]);
}

// ---------- K2: hist (blocks 0..hblocks-1) ∥ gemm slice ----------
__global__ __launch_bounds__(256) void hist_gemm_k(
    const void* __restrict__ ei, int E,
    unsigned* __restrict__ packed, int* __restrict__ bucket_count,
    int* __restrict__ done, int* __restrict__ bcur, int* __restrict__ bucket_base,
    int hblocks,
    const float* __restrict__ h, const ushort* __restrict__ Wbf,
    const float* __restrict__ a, ushort* __restrict__ Whb,
    float* __restrict__ asrc, float* __restrict__ adst, int N, int gb0) {
  __shared__ int lh[MAXB];
  __shared__ int wsum[4];
  __shared__ int last;
  int tid = (int)threadIdx.x;

  if ((int)blockIdx.x >= hblocks) {
    gemm_body((int)blockIdx.x - hblocks + gb0, h, Wbf, a, Whb, asrc, adst, N);
    return;
  }

  // ===== hist body =====
  lh[tid] = 0;
  __syncthreads();

  const int* p32 = (const int*)ei;
  bool is64 = true;
#pragma unroll
  for (int i = 0; i < 32; ++i) is64 = is64 && (p32[2 * i + 1] == 0);
  const long long* p64 = (const long long*)ei;
  int stride = hblocks * 256;
  for (int e = blockIdx.x * 256 + tid; e < E; e += stride) {
    int r, c;
    if (is64) { r = (int)p64[e]; c = (int)p64[E + e]; }
    else      { r = p32[e];      c = p32[E + e]; }
    packed[e] = ((unsigned)c << 16) | (unsigned)r;
    atomicAdd(&lh[c >> BSHIFT], 1);
  }
  __syncthreads();
  if (lh[tid]) atomicAdd(&bucket_count[tid], lh[tid]);
  __syncthreads();               // all of this block's adds issued & drained...
  if (tid == 0) {
    __threadfence();             // ...and device-visible before signaling
    int old = atomicAdd(done, 1);
    last = (old == hblocks - 1);
  }
  __syncthreads();
  if (!last) return;
  __threadfence();               // acquire

  int lane = tid & 63, wid = tid >> 6;
  int v = atomicAdd(&bucket_count[tid], 0);
  int x = v;
#pragma unroll
  for (int off = 1; off < 64; off <<= 1) {
    int t = __shfl_up(x, off);
    if (lane >= off) x += t;
  }
  if (lane == 63) wsum[wid] = x;
  __syncthreads();
  int woff = 0;
  for (int w = 0; w < wid; ++w) woff += wsum[w];
  int excl = woff + x - v;
  bcur[tid] = excl;
  bucket_base[tid] = excl;
  if (tid == 255) bucket_base[256] = excl + v;
}

// ---------- K3: bin (blocks 0..eblk-1, 2048-edge tiles) ∥ gemm slice ----------
#define TILE2 2048
__global__ __launch_bounds__(256) void bin_gemm_k(
    const unsigned* __restrict__ packed, int* __restrict__ bcur,
    unsigned* __restrict__ bin_buf, int E, int eblk,
    const float* __restrict__ h, const ushort* __restrict__ Wbf,
    const float* __restrict__ a, ushort* __restrict__ Whb,
    float* __restrict__ asrc, float* __restrict__ adst, int N, int gb0) {
  __shared__ int lhist[MAXB];
  __shared__ int lbase[MAXB];
  int tid = (int)threadIdx.x;

  if ((int)blockIdx.x >= eblk) {
    gemm_body((int)blockIdx.x - eblk + gb0, h, Wbf, a, Whb, asrc, adst, N);
    return;
  }

  int t0 = blockIdx.x * TILE2;
  lhist[tid] = 0;
  __syncthreads();

  unsigned rec[8];
  int rb[8], rr[8];
#pragma unroll
  for (int k = 0; k < 8; ++k) {
    int i = t0 + tid + k * 256;
    rb[k] = -1;
    if (i < E) {
      rec[k] = packed[i];
      rb[k] = (int)(rec[k] >> (16 + BSHIFT));
      rr[k] = atomicAdd(&lhist[rb[k]], 1);
    }
  }
  __syncthreads();
  lbase[tid] = lhist[tid] ? atomicAdd(&bcur[tid], lhist[tid]) : 0;
  __syncthreads();
#pragma unroll
  for (int k = 0; k < 8; ++k) {
    if (rb[k] >= 0) bin_buf[lbase[rb[k]] + rr[k]] = rec[k];
  }
}

// ---------- K4: perm3 (blocks 0..nbuckets-1) ∥ gemm slice ----------
__global__ __launch_bounds__(256) void perm_gemm_k(
    const unsigned* __restrict__ bin_buf, const int* __restrict__ bucket_base,
    int* __restrict__ rowptr, ushort* __restrict__ row_sorted, int nbuckets,
    const float* __restrict__ h, const ushort* __restrict__ Wbf,
    const float* __restrict__ a, ushort* __restrict__ Whb,
    float* __restrict__ asrc, float* __restrict__ adst, int N, int gb0) {
  __shared__ int hist[MAXB];
  __shared__ int cur[MAXB];
  __shared__ int wsum[4];
  int tid = (int)threadIdx.x;

  if ((int)blockIdx.x >= nbuckets) {
    gemm_body((int)blockIdx.x - nbuckets + gb0, h, Wbf, a, Whb, asrc, adst, N);
    return;
  }

  int b = (int)blockIdx.x;
  int c0 = b << BSHIFT;
  int ncol = min(MAXB, N - c0);
  int e0 = bucket_base[b], e1 = bucket_base[b + 1];

  hist[tid] = 0;
  __syncthreads();
  for (int i = e0 + tid; i < e1; i += 256) {
    int cl = (int)(bin_buf[i] >> 16) - c0;
    if ((unsigned)cl < (unsigned)MAXB) atomicAdd(&hist[cl], 1);  // defensive bound
  }
  __syncthreads();

  int lane = tid & 63, wid = tid >> 6;
  int v = hist[tid];
  int x = v;
#pragma unroll
  for (int off = 1; off < 64; off <<= 1) {
    int t = __shfl_up(x, off);
    if (lane >= off) x += t;
  }
  if (lane == 63) wsum[wid] = x;
  __syncthreads();
  int woff = 0;
  for (int w = 0; w < wid; ++w) woff += wsum[w];
  int excl = woff + x - v;
  cur[tid] = e0 + excl;
  if (tid < ncol) rowptr[c0 + tid] = e0 + excl;
  if (b == nbuckets - 1 && tid == 0) rowptr[c0 + ncol] = e1;  // rowptr[N]
  __syncthreads();

  for (int i = e0 + tid; i < e1; i += 256) {
    unsigned rec = bin_buf[i];
    int cl = (int)(rec >> 16) - c0;
    if ((unsigned)cl < (unsigned)MAXB) {
      int p = atomicAdd(&cur[cl], 1);
      row_sorted[p] = (ushort)(rec & 0xffffu);
    }
  }
}

// ---------- K5: fused softmax + aggregation + ELU (one wave per node, no LDS) ----------
// Whb rows are PERMUTED (slot s = lm*8+n0 -> true col n0*16+lm). Lane j's u32 holds
// slots {2j, 2j+1} -> true cols c0 = 32*(j&3) + (j>>2) and c0+16.
__global__ __launch_bounds__(256) void softagg_k(const int* __restrict__ rowptr,
                                                 const ushort* __restrict__ row_sorted,
                                                 const float* __restrict__ asrc,
                                                 const float* __restrict__ adst,
                                                 const ushort* __restrict__ Whb,
                                                 float* __restrict__ out, int N) {
  int node = blockIdx.x * 4 + ((int)threadIdx.x >> 6);
  if (node >= N) return;
  int lane = (int)threadIdx.x & 63;
  int beg = rowptr[node], end = rowptr[node + 1];
  int deg = end - beg;
  float adc = adst[node];
  float ax = 0.f, ay = 0.f;

  if (deg <= 64) {
    int r = 0;
    float v = NEG_BIG;
    if (lane < deg) {
      r = row_sorted[beg + lane];
      v = asrc[r] + adc;
      v = (v >= 0.f) ? v : 0.2f * v;
    }
    float m = v;
#pragma unroll
    for (int off = 32; off > 0; off >>= 1) m = fmaxf(m, __shfl_xor(m, off));
    float e = (lane < deg) ? __expf(v - m) : 0.f;
    float s = e;
#pragma unroll
    for (int off = 32; off > 0; off >>= 1) s += __shfl_xor(s, off);
    float w = e / (s + 1e-16f);

    int j = 0;
    for (; j + 7 < deg; j += 8) {
      float wv[8];
      int rv[8];
#pragma unroll
      for (int q = 0; q < 8; ++q) { wv[q] = __shfl(w, j + q); rv[q] = __shfl(r, j + q); }
      unsigned u[8];
#pragma unroll
      for (int q = 0; q < 8; ++q) u[q] = ((const unsigned*)(Whb + (size_t)rv[q] * 128))[lane];
#pragma unroll
      for (int q = 0; q < 8; ++q) { ax += wv[q] * bf_lo(u[q]); ay += wv[q] * bf_hi(u[q]); }
    }
    for (; j < deg; ++j) {
      float wj = __shfl(w, j);
      int rj = __shfl(r, j);
      unsigned u = ((const unsigned*)(Whb + (size_t)rj * 128))[lane];
      ax += wj * bf_lo(u); ay += wj * bf_hi(u);
    }
  } else {
    float m = NEG_BIG, s = 0.f;
    for (int i = beg + lane; i < end; i += 64) {
      float v = asrc[row_sorted[i]] + adc;
      v = (v >= 0.f) ? v : 0.2f * v;
      if (v > m) { s = s * __expf(m - v) + 1.f; m = v; }
      else       { s += __expf(v - m); }
    }
#pragma unroll
    for (int off = 32; off > 0; off >>= 1) {
      float mo = __shfl_xor(m, off);
      float so = __shfl_xor(s, off);
      float M = fmaxf(m, mo);
      s = s * __expf(m - M) + so * __expf(mo - M);
      m = M;
    }
    float inv = 1.f / (s + 1e-16f);
    for (int i = beg; i < end; ++i) {
      int rj = row_sorted[i];
      float v = asrc[rj] + adc;
      v = (v >= 0.f) ? v : 0.2f * v;
      float wj = __expf(v - m) * inv;
      unsigned u = ((const unsigned*)(Whb + (size_t)rj * 128))[lane];
      ax += wj * bf_lo(u); ay += wj * bf_hi(u);
    }
  }

  ax = ax > 0.f ? ax : expm1f(ax);
  ay = ay > 0.f ? ay : expm1f(ay);
  int c0 = ((lane & 3) << 5) + (lane >> 2);
  float* orow = out + (size_t)node * 128;
  orow[c0] = ax;
  orow[c0 + 16] = ay;
}

extern "C" void kernel_launch(void* const* d_in, const int* in_sizes, int n_in,
                              void* d_out, int out_size, void* d_ws, size_t ws_size,
                              hipStream_t stream) {
  const float* h = (const float*)d_in[0];
  const void* ei = d_in[1];
  const float* W = (const float*)d_in[2];
  const float* a = (const float*)d_in[3];
  int N = in_sizes[0] / 128;
  int E = in_sizes[1] / 2;
  float* out = (float*)d_out;

  // workspace layout:
  // Whb[N*128 u16] | asrc[N] f32 | adst[N] f32 | bucket_count[256] | done[1]+pad |
  // bcur[256] | bucket_base[257]+pad | rowptr[N+1] | bin_buf[E] u32 | packed[E] u32 |
  // row_sorted[E] u16 | Wbf[16384] u16
  ushort* Whb = (ushort*)d_ws;
  float* asrc = (float*)(Whb + (size_t)N * 128);
  float* adst = asrc + N;
  int* bucket_count = (int*)(adst + N);
  int* done = bucket_count + MAXB;
  int* bcur = done + 4;
  int* bucket_base = bcur + MAXB;
  int* rowptr = bucket_base + MAXB + 4;
  unsigned* bin_buf = (unsigned*)(rowptr + N + 1);
  unsigned* packed = bin_buf + E;
  ushort* row_sorted = (ushort*)(packed + E);
  ushort* Wbf = row_sorted + E;

  int nbuckets = (N + MAXB - 1) >> BSHIFT;     // 196
  const int HBLOCKS = 256;
  int eblk = (E + TILE2 - 1) / TILE2;          // 391 bin tiles
  int gtot = (N + 63) / 64;                    // 782 gemm blocks
  int G1 = gtot / 3;                           // slice for d2
  int G2 = (gtot - G1) / 2;                    // slice for d3
  int G3 = gtot - G1 - G2;                     // slice for d4

  wprep_k<<<64, 256, 0, stream>>>(W, Wbf, bucket_count, done);
  hist_gemm_k<<<HBLOCKS + G1, 256, 0, stream>>>(
      ei, E, packed, bucket_count, done, bcur, bucket_base, HBLOCKS,
      h, Wbf, a, Whb, asrc, adst, N, 0);
  bin_gemm_k<<<eblk + G2, 256, 0, stream>>>(
      packed, bcur, bin_buf, E, eblk,
      h, Wbf, a, Whb, asrc, adst, N, G1);
  perm_gemm_k<<<nbuckets + G3, 256, 0, stream>>>(
      bin_buf, bucket_base, rowptr, row_sorted, nbuckets,
      h, Wbf, a, Whb, asrc, adst, N, G1 + G2);
  softagg_k<<<(N + 3) / 4, 256, 0, stream>>>(rowptr, row_sorted, asrc, adst, Whb, out, N);
}

// Round 15
// 95.534 us; speedup vs baseline: 1.0488x; 1.0488x over previous
//
#include <hip/hip_runtime.h>
#include <math.h>

#define NEG_BIG -1.0e30f
#define BSHIFT 8                 // bucket = 256 target-node ids
#define MAXB 256

typedef __attribute__((ext_vector_type(8))) short short8v;   // 8 bf16
typedef __attribute__((ext_vector_type(4))) float f32x4;

__device__ __forceinline__ ushort f2bf(float f) {
  unsigned u = __float_as_uint(f);
  unsigned r = (u + 0x7fffu + ((u >> 16) & 1u)) >> 16;  // round-to-nearest-even
  return (ushort)r;
}
__device__ __forceinline__ float bf_lo(unsigned u) { return __uint_as_float(u << 16); }
__device__ __forceinline__ float bf_hi(unsigned u) { return __uint_as_float(u & 0xffff0000u); }

// ================= gemm waves (device fn) =================
// Each wave computes 16 rows x 128 cols: row base = base + 16*(tid>>6).
// Works for any block size that is a multiple of 64.
// k-map (applied identically to A and B -> result layout-invariant): k = kk*32+lg*8+i
// Whb PERMUTED row layout: Whb[r][lm*8 + n0] holds true col (n0*16 + lm).
__device__ __forceinline__ void gemm_waves(int base, const float* __restrict__ h,
                                           const ushort* __restrict__ Wbf,
                                           const float* __restrict__ a,
                                           ushort* __restrict__ Whb,
                                           float* __restrict__ asrc,
                                           float* __restrict__ adst, int N) {
  int tid = (int)threadIdx.x;
  int l = tid & 63;
  int lg = l >> 4;
  int lm = l & 15;
  int r0 = base + 16 * (tid >> 6);
  const short8v* Wb8 = (const short8v*)Wbf;

  float as_v[8], ad_v[8];
#pragma unroll
  for (int n0 = 0; n0 < 8; ++n0) {
    as_v[n0] = a[n0 * 16 + lm];
    ad_v[n0] = a[128 + n0 * 16 + lm];
  }

  f32x4 acc[8];
#pragma unroll
  for (int n0 = 0; n0 < 8; ++n0) acc[n0] = (f32x4){0.f, 0.f, 0.f, 0.f};

  int arow = r0 + lm;
  const float* hrow = h + (size_t)arow * 128;
  bool rok = (arow < N);

#pragma unroll
  for (int kk = 0; kk < 4; ++kk) {
    short8v av;
    if (rok) {
      const float4* hp = (const float4*)(hrow + kk * 32 + lg * 8);
      float4 x0 = hp[0], x1 = hp[1];
      av[0] = (short)f2bf(x0.x); av[1] = (short)f2bf(x0.y);
      av[2] = (short)f2bf(x0.z); av[3] = (short)f2bf(x0.w);
      av[4] = (short)f2bf(x1.x); av[5] = (short)f2bf(x1.y);
      av[6] = (short)f2bf(x1.z); av[7] = (short)f2bf(x1.w);
    } else {
      av = (short8v){0, 0, 0, 0, 0, 0, 0, 0};
    }
#pragma unroll
    for (int n0 = 0; n0 < 8; ++n0) {
      short8v bv = Wb8[(kk * 8 + n0) * 64 + l];
      acc[n0] = __builtin_amdgcn_mfma_f32_16x16x32_bf16(av, bv, acc[n0], 0, 0, 0);
    }
  }

#pragma unroll
  for (int reg = 0; reg < 4; ++reg) {
    int r = r0 + lg * 4 + reg;
    if (r < N) {
      short8v pk;
#pragma unroll
      for (int n0 = 0; n0 < 8; ++n0) pk[n0] = (short)f2bf(acc[n0][reg]);
      *(short8v*)(Whb + (size_t)r * 128 + lm * 8) = pk;
    }
  }

#pragma unroll
  for (int reg = 0; reg < 4; ++reg) {
    float ps = 0.f, pd = 0.f;
#pragma unroll
    for (int n0 = 0; n0 < 8; ++n0) {
      ps += acc[n0][reg] * as_v[n0];
      pd += acc[n0][reg] * ad_v[n0];
    }
#pragma unroll
    for (int off = 1; off < 16; off <<= 1) {
      ps += __shfl_xor(ps, off);
      pd += __shfl_xor(pd, off);
    }
    int r = r0 + lg * 4 + reg;
    if (lm == 0 && r < N) { asrc[r] = ps; adst[r] = pd; }
  }
}

// ---------- K1: W pack (bf16 MFMA B-fragment order) + zero bucket_count/done ----------
__global__ void wprep_k(const float* __restrict__ W, ushort* __restrict__ Wbf,
                        int* __restrict__ bucket_count, int* __restrict__ done) {
  int j = blockIdx.x * blockDim.x + threadIdx.x;
  if (j < MAXB) bucket_count[j] = 0;
  if (j == 0) *done = 0;
  if (j >= 128 * 128) return;
  int i = j & 7;
  int l = (j >> 3) & 63;
  int n0 = (j >> 9) & 7;
  int kk = j >> 12;
  int k = kk * 32 + ((l >> 4) & 3) * 8 + i;
  int n = n0 * 16 + (l & 15);
  Wbf[j] = f2bf(W[k * 128 + n]);
}

// ---------- K2 (256 thr): hist (blocks 0..hblocks-1) ∥ gemm slice (64 rows/block) ----------
__global__ __launch_bounds__(256) void hist_gemm_k(
    const void* __restrict__ ei, int E,
    unsigned* __restrict__ packed, int* __restrict__ bucket_count,
    int* __restrict__ done, int* __restrict__ bcur, int* __restrict__ bucket_base,
    int hblocks,
    const float* __restrict__ h, const ushort* __restrict__ Wbf,
    const float* __restrict__ a, ushort* __restrict__ Whb,
    float* __restrict__ asrc, float* __restrict__ adst, int N) {
  __shared__ int lh[MAXB];
  __shared__ int wsum[4];
  __shared__ int last;
  int tid = (int)threadIdx.x;

  if ((int)blockIdx.x >= hblocks) {
    gemm_waves(((int)blockIdx.x - hblocks) * 64, h, Wbf, a, Whb, asrc, adst, N);
    return;
  }

  // ===== hist body (R13-proven) =====
  lh[tid] = 0;
  __syncthreads();

  const int* p32 = (const int*)ei;
  bool is64 = true;
#pragma unroll
  for (int i = 0; i < 32; ++i) is64 = is64 && (p32[2 * i + 1] == 0);
  const long long* p64 = (const long long*)ei;
  int stride = hblocks * 256;
  for (int e = blockIdx.x * 256 + tid; e < E; e += stride) {
    int r, c;
    if (is64) { r = (int)p64[e]; c = (int)p64[E + e]; }
    else      { r = p32[e];      c = p32[E + e]; }
    packed[e] = ((unsigned)c << 16) | (unsigned)r;
    atomicAdd(&lh[c >> BSHIFT], 1);
  }
  __syncthreads();
  if (lh[tid]) atomicAdd(&bucket_count[tid], lh[tid]);
  __syncthreads();               // all of this block's adds issued & drained...
  if (tid == 0) {
    __threadfence();             // ...and device-visible before signaling
    int old = atomicAdd(done, 1);
    last = (old == hblocks - 1);
  }
  __syncthreads();
  if (!last) return;
  __threadfence();               // acquire

  int lane = tid & 63, wid = tid >> 6;
  int v = atomicAdd(&bucket_count[tid], 0);
  int x = v;
#pragma unroll
  for (int off = 1; off < 64; off <<= 1) {
    int t = __shfl_up(x, off);
    if (lane >= off) x += t;
  }
  if (lane == 63) wsum[wid] = x;
  __syncthreads();
  int woff = 0;
  for (int w = 0; w < wid; ++w) woff += wsum[w];
  int excl = woff + x - v;
  bcur[tid] = excl;
  bucket_base[tid] = excl;
  if (tid == 255) bucket_base[256] = excl + v;
}

// ---------- K3 (1024 thr): bin (blocks 0..eblk-1, TILE 8192) ∥ gemm slice (256 rows/block) ----------
#define TILE 8192
__global__ __launch_bounds__(1024) void bin_gemm_k(
    const unsigned* __restrict__ packed, int* __restrict__ bcur,
    unsigned* __restrict__ bin_buf, int E, int eblk,
    const float* __restrict__ h, const ushort* __restrict__ Wbf,
    const float* __restrict__ a, ushort* __restrict__ Whb,
    float* __restrict__ asrc, float* __restrict__ adst, int N, int gbase) {
  __shared__ int lhist[MAXB];
  __shared__ int lbase[MAXB];
  int tid = (int)threadIdx.x;

  if ((int)blockIdx.x >= eblk) {
    gemm_waves(gbase + ((int)blockIdx.x - eblk) * 256, h, Wbf, a, Whb, asrc, adst, N);
    return;
  }

  // ===== bin body (R13-proven: 1024 thr, TILE 8192) =====
  int t0 = blockIdx.x * TILE;
  if (tid < MAXB) lhist[tid] = 0;
  __syncthreads();

  unsigned rec[8];
  int rb[8], rr[8];
#pragma unroll
  for (int k = 0; k < 8; ++k) {
    int i = t0 + tid + k * 1024;
    rb[k] = -1;
    if (i < E) {
      rec[k] = packed[i];
      rb[k] = (int)(rec[k] >> (16 + BSHIFT));
      rr[k] = atomicAdd(&lhist[rb[k]], 1);
    }
  }
  __syncthreads();
  if (tid < MAXB) lbase[tid] = lhist[tid] ? atomicAdd(&bcur[tid], lhist[tid]) : 0;
  __syncthreads();
#pragma unroll
  for (int k = 0; k < 8; ++k) {
    if (rb[k] >= 0) bin_buf[lbase[rb[k]] + rr[k]] = rec[k];
  }
}

// ---------- K4 (1024 thr): perm3 (blocks 0..nbuckets-1) ∥ gemm slice (256 rows/block) ----------
__global__ __launch_bounds__(1024) void perm_gemm_k(
    const unsigned* __restrict__ bin_buf, const int* __restrict__ bucket_base,
    int* __restrict__ rowptr, ushort* __restrict__ row_sorted, int N, int nbuckets,
    const float* __restrict__ h, const ushort* __restrict__ Wbf,
    const float* __restrict__ a, ushort* __restrict__ Whb,
    float* __restrict__ asrc, float* __restrict__ adst, int gbase) {
  __shared__ int hist[MAXB];
  __shared__ int cur[MAXB];
  __shared__ int wsum[16];
  int tid = (int)threadIdx.x;

  if ((int)blockIdx.x >= nbuckets) {
    gemm_waves(gbase + ((int)blockIdx.x - nbuckets) * 256, h, Wbf, a, Whb, asrc, adst, N);
    return;
  }

  // ===== perm3 body (R13-proven: 1024 thr) =====
  int b = (int)blockIdx.x;
  int c0 = b << BSHIFT;
  int ncol = min(MAXB, N - c0);
  int e0 = bucket_base[b], e1 = bucket_base[b + 1];

  if (tid < MAXB) hist[tid] = 0;
  __syncthreads();
  for (int i = e0 + tid; i < e1; i += 1024) {
    int cl = (int)(bin_buf[i] >> 16) - c0;
    if ((unsigned)cl < (unsigned)MAXB) atomicAdd(&hist[cl], 1);  // defensive bound
  }
  __syncthreads();

  int lane = tid & 63, wid = tid >> 6;
  int v = (tid < MAXB) ? hist[tid] : 0;
  int x = v;
#pragma unroll
  for (int off = 1; off < 64; off <<= 1) {
    int t = __shfl_up(x, off);
    if (lane >= off) x += t;
  }
  if (lane == 63) wsum[wid] = x;
  __syncthreads();
  if (tid < MAXB) {
    int woff = 0;
    for (int w = 0; w < wid; ++w) woff += wsum[w];
    int excl = woff + x - v;
    cur[tid] = e0 + excl;
    if (tid < ncol) rowptr[c0 + tid] = e0 + excl;
  }
  if (b == nbuckets - 1 && tid == 0) rowptr[N] = e1;
  __syncthreads();

  for (int i = e0 + tid; i < e1; i += 1024) {
    unsigned rec = bin_buf[i];
    int cl = (int)(rec >> 16) - c0;
    if ((unsigned)cl < (unsigned)MAXB) {
      int p = atomicAdd(&cur[cl], 1);
      row_sorted[p] = (ushort)(rec & 0xffffu);
    }
  }
}

// ---------- K5: fused softmax + aggregation + ELU (one wave per node, no LDS) ----------
// Whb rows are PERMUTED (slot s = lm*8+n0 -> true col n0*16+lm). Lane j's u32 holds
// slots {2j, 2j+1} -> true cols c0 = 32*(j&3) + (j>>2) and c0+16.
__global__ __launch_bounds__(256) void softagg_k(const int* __restrict__ rowptr,
                                                 const ushort* __restrict__ row_sorted,
                                                 const float* __restrict__ asrc,
                                                 const float* __restrict__ adst,
                                                 const ushort* __restrict__ Whb,
                                                 float* __restrict__ out, int N) {
  int node = blockIdx.x * 4 + ((int)threadIdx.x >> 6);
  if (node >= N) return;
  int lane = (int)threadIdx.x & 63;
  int beg = rowptr[node], end = rowptr[node + 1];
  int deg = end - beg;
  float adc = adst[node];
  float ax = 0.f, ay = 0.f;

  if (deg <= 64) {
    int r = 0;
    float v = NEG_BIG;
    if (lane < deg) {
      r = row_sorted[beg + lane];
      v = asrc[r] + adc;
      v = (v >= 0.f) ? v : 0.2f * v;
    }
    float m = v;
#pragma unroll
    for (int off = 32; off > 0; off >>= 1) m = fmaxf(m, __shfl_xor(m, off));
    float e = (lane < deg) ? __expf(v - m) : 0.f;
    float s = e;
#pragma unroll
    for (int off = 32; off > 0; off >>= 1) s += __shfl_xor(s, off);
    float w = e / (s + 1e-16f);

    int j = 0;
    for (; j + 7 < deg; j += 8) {
      float wv[8];
      int rv[8];
#pragma unroll
      for (int q = 0; q < 8; ++q) { wv[q] = __shfl(w, j + q); rv[q] = __shfl(r, j + q); }
      unsigned u[8];
#pragma unroll
      for (int q = 0; q < 8; ++q) u[q] = ((const unsigned*)(Whb + (size_t)rv[q] * 128))[lane];
#pragma unroll
      for (int q = 0; q < 8; ++q) { ax += wv[q] * bf_lo(u[q]); ay += wv[q] * bf_hi(u[q]); }
    }
    for (; j < deg; ++j) {
      float wj = __shfl(w, j);
      int rj = __shfl(r, j);
      unsigned u = ((const unsigned*)(Whb + (size_t)rj * 128))[lane];
      ax += wj * bf_lo(u); ay += wj * bf_hi(u);
    }
  } else {
    float m = NEG_BIG, s = 0.f;
    for (int i = beg + lane; i < end; i += 64) {
      float v = asrc[row_sorted[i]] + adc;
      v = (v >= 0.f) ? v : 0.2f * v;
      if (v > m) { s = s * __expf(m - v) + 1.f; m = v; }
      else       { s += __expf(v - m); }
    }
#pragma unroll
    for (int off = 32; off > 0; off >>= 1) {
      float mo = __shfl_xor(m, off);
      float so = __shfl_xor(s, off);
      float M = fmaxf(m, mo);
      s = s * __expf(m - M) + so * __expf(mo - M);
      m = M;
    }
    float inv = 1.f / (s + 1e-16f);
    for (int i = beg; i < end; ++i) {
      int rj = row_sorted[i];
      float v = asrc[rj] + adc;
      v = (v >= 0.f) ? v : 0.2f * v;
      float wj = __expf(v - m) * inv;
      unsigned u = ((const unsigned*)(Whb + (size_t)rj * 128))[lane];
      ax += wj * bf_lo(u); ay += wj * bf_hi(u);
    }
  }

  ax = ax > 0.f ? ax : expm1f(ax);
  ay = ay > 0.f ? ay : expm1f(ay);
  int c0 = ((lane & 3) << 5) + (lane >> 2);
  float* orow = out + (size_t)node * 128;
  orow[c0] = ax;
  orow[c0 + 16] = ay;
}

extern "C" void kernel_launch(void* const* d_in, const int* in_sizes, int n_in,
                              void* d_out, int out_size, void* d_ws, size_t ws_size,
                              hipStream_t stream) {
  const float* h = (const float*)d_in[0];
  const void* ei = d_in[1];
  const float* W = (const float*)d_in[2];
  const float* a = (const float*)d_in[3];
  int N = in_sizes[0] / 128;
  int E = in_sizes[1] / 2;
  float* out = (float*)d_out;

  // workspace layout:
  // Whb[N*128 u16] | asrc[N] f32 | adst[N] f32 | bucket_count[256] | done[1]+pad |
  // bcur[256] | bucket_base[257]+pad | rowptr[N+1] | bin_buf[E] u32 | packed[E] u32 |
  // row_sorted[E] u16 | Wbf[16384] u16
  ushort* Whb = (ushort*)d_ws;
  float* asrc = (float*)(Whb + (size_t)N * 128);
  float* adst = asrc + N;
  int* bucket_count = (int*)(adst + N);
  int* done = bucket_count + MAXB;
  int* bcur = done + 4;
  int* bucket_base = bcur + MAXB;
  int* rowptr = bucket_base + MAXB + 4;
  unsigned* bin_buf = (unsigned*)(rowptr + N + 1);
  unsigned* packed = bin_buf + E;
  ushort* row_sorted = (ushort*)(packed + E);
  ushort* Wbf = row_sorted + E;

  int nbuckets = (N + MAXB - 1) >> BSHIFT;     // 196
  const int HBLOCKS = 256;
  int eblk = (E + TILE - 1) / TILE;            // 98 bin tiles (1024 thr each)

  // gemm slicing: d2 takes ~1/3 in 64-row units; d3/d4 split the rest in 256-row units
  int gtiles = (N + 63) / 64;                  // 782 x 64-row tiles
  int t1 = gtiles / 3;                         // 260 tiles -> d2
  int rows_rem = (gtiles - t1) * 64;           // remaining rows
  int nb34 = (rows_rem + 255) / 256;           // 256-row blocks for d3+d4
  int nb3 = (nb34 + 1) / 2;
  int nb4 = nb34 - nb3;
  int base3 = t1 * 64;
  int base4 = base3 + nb3 * 256;

  wprep_k<<<64, 256, 0, stream>>>(W, Wbf, bucket_count, done);
  hist_gemm_k<<<HBLOCKS + t1, 256, 0, stream>>>(
      ei, E, packed, bucket_count, done, bcur, bucket_base, HBLOCKS,
      h, Wbf, a, Whb, asrc, adst, N);
  bin_gemm_k<<<eblk + nb3, 1024, 0, stream>>>(
      packed, bcur, bin_buf, E, eblk,
      h, Wbf, a, Whb, asrc, adst, N, base3);
  perm_gemm_k<<<nbuckets + nb4, 1024, 0, stream>>>(
      bin_buf, bucket_base, rowptr, row_sorted, N, nbuckets,
      h, Wbf, a, Whb, asrc, adst, base4);
  softagg_k<<<(N + 3) / 4, 256, 0, stream>>>(rowptr, row_sorted, asrc, adst, Whb, out, N);
}

// Round 16
// 86.286 us; speedup vs baseline: 1.1612x; 1.1072x over previous
//
#include <hip/hip_runtime.h>
#include <math.h>

#define NEG_BIG -1.0e30f
#define BSHIFT 8                 // bucket = 256 target-node ids
#define MAXB 256

typedef __attribute__((ext_vector_type(8))) short short8v;   // 8 bf16
typedef __attribute__((ext_vector_type(4))) float f32x4;

__device__ __forceinline__ ushort f2bf(float f) {
  unsigned u = __float_as_uint(f);
  unsigned r = (u + 0x7fffu + ((u >> 16) & 1u)) >> 16;  // round-to-nearest-even
  return (ushort)r;
}
__device__ __forceinline__ float bf_lo(unsigned u) { return __uint_as_float(u << 16); }
__device__ __forceinline__ float bf_hi(unsigned u) { return __uint_as_float(u & 0xffff0000u); }

// ---------- K1: W pack (bf16 MFMA B-fragment order) + zero bucket_count/done ----------
__global__ void wprep_k(const float* __restrict__ W, ushort* __restrict__ Wbf,
                        int* __restrict__ bucket_count, int* __restrict__ done) {
  int j = blockIdx.x * blockDim.x + threadIdx.x;
  if (j < MAXB) bucket_count[j] = 0;
  if (j == 0) *done = 0;
  if (j >= 128 * 128) return;
  int i = j & 7;
  int l = (j >> 3) & 63;
  int n0 = (j >> 9) & 7;
  int kk = j >> 12;
  int k = kk * 32 + ((l >> 4) & 3) * 8 + i;
  int n = n0 * 16 + (l & 15);
  Wbf[j] = f2bf(W[k * 128 + n]);
}

// ---------- K2: fused histB (blocks 0..hblocks-1) ∥ gemm (blocks hblocks..) ----------
// histB: convert + pack (col<<16)|row + bucket histogram; last histB block scans.
// gemm: Wh = h @ W via MFMA bf16, B-fragments LDS-staged -> permuted Whb + fused alpha.
// NOTE: requires N < 65536; N = 50000 here.
__global__ __launch_bounds__(256) void hist_gemm_k(
    const void* __restrict__ ei, int E,
    unsigned* __restrict__ packed, int* __restrict__ bucket_count,
    int* __restrict__ done, int* __restrict__ bcur, int* __restrict__ bucket_base,
    int hblocks,
    const float* __restrict__ h, const ushort* __restrict__ Wbf,
    const float* __restrict__ a, ushort* __restrict__ Whb,
    float* __restrict__ asrc, float* __restrict__ adst, int N) {
  __shared__ ushort Bs[16384];   // 32 KB: whole Wbf, staged once per gemm block
  __shared__ int lh[MAXB];
  __shared__ int wsum[4];
  __shared__ int last;
  int tid = (int)threadIdx.x;

  if ((int)blockIdx.x < hblocks) {
    // ================= histB body (R13-proven) =================
    lh[tid] = 0;
    __syncthreads();

    const int* p32 = (const int*)ei;
    bool is64 = true;
#pragma unroll
    for (int i = 0; i < 32; ++i) is64 = is64 && (p32[2 * i + 1] == 0);
    const long long* p64 = (const long long*)ei;
    int stride = hblocks * 256;
    for (int e = blockIdx.x * 256 + tid; e < E; e += stride) {
      int r, c;
      if (is64) { r = (int)p64[e]; c = (int)p64[E + e]; }
      else      { r = p32[e];      c = p32[E + e]; }
      packed[e] = ((unsigned)c << 16) | (unsigned)r;
      atomicAdd(&lh[c >> BSHIFT], 1);
    }
    __syncthreads();
    if (lh[tid]) atomicAdd(&bucket_count[tid], lh[tid]);
    __syncthreads();               // all of this block's adds issued & drained...
    if (tid == 0) {
      __threadfence();             // ...and device-visible before signaling
      int old = atomicAdd(done, 1);
      last = (old == hblocks - 1);
    }
    __syncthreads();
    if (!last) return;
    __threadfence();               // acquire

    int lane = tid & 63, wid = tid >> 6;
    int v = atomicAdd(&bucket_count[tid], 0);
    int x = v;
#pragma unroll
    for (int off = 1; off < 64; off <<= 1) {
      int t = __shfl_up(x, off);
      if (lane >= off) x += t;
    }
    if (lane == 63) wsum[wid] = x;
    __syncthreads();
    int woff = 0;
    for (int w = 0; w < wid; ++w) woff += wsum[w];
    int excl = woff + x - v;
    bcur[tid] = excl;
    bucket_base[tid] = excl;
    if (tid == 255) bucket_base[256] = excl + v;
    return;
  }

  // ================= gemm body =================
  // k-map (applied identically to A and B -> result layout-invariant): k = kk*32+lg*8+i
  // Whb PERMUTED row layout: Whb[r][lm*8 + n0] holds true col (n0*16 + lm).

  // stage Wbf -> LDS (coalesced 16B chunks; L2-hot source)
  {
    const ulong2* src = (const ulong2*)Wbf;
    ulong2* dst = (ulong2*)Bs;
#pragma unroll
    for (int i = 0; i < 8; ++i) dst[i * 256 + tid] = src[i * 256 + tid];
  }
  __syncthreads();

  int gb = (int)blockIdx.x - hblocks;
  int w = tid >> 6;
  int l = tid & 63;
  int lg = l >> 4;
  int lm = l & 15;
  int r0 = gb * 64 + 16 * w;
  const short8v* Bs8 = (const short8v*)Bs;

  float as_v[8], ad_v[8];
#pragma unroll
  for (int n0 = 0; n0 < 8; ++n0) {
    as_v[n0] = a[n0 * 16 + lm];
    ad_v[n0] = a[128 + n0 * 16 + lm];
  }

  f32x4 acc[8];
#pragma unroll
  for (int n0 = 0; n0 < 8; ++n0) acc[n0] = (f32x4){0.f, 0.f, 0.f, 0.f};

  int arow = r0 + lm;
  const float* hrow = h + (size_t)arow * 128;
  bool rok = (arow < N);

#pragma unroll
  for (int kk = 0; kk < 4; ++kk) {
    short8v av;
    if (rok) {
      const float4* hp = (const float4*)(hrow + kk * 32 + lg * 8);
      float4 x0 = hp[0], x1 = hp[1];
      av[0] = (short)f2bf(x0.x); av[1] = (short)f2bf(x0.y);
      av[2] = (short)f2bf(x0.z); av[3] = (short)f2bf(x0.w);
      av[4] = (short)f2bf(x1.x); av[5] = (short)f2bf(x1.y);
      av[6] = (short)f2bf(x1.z); av[7] = (short)f2bf(x1.w);
    } else {
      av = (short8v){0, 0, 0, 0, 0, 0, 0, 0};
    }
#pragma unroll
    for (int n0 = 0; n0 < 8; ++n0) {
      short8v bv = Bs8[(kk * 8 + n0) * 64 + l];
      acc[n0] = __builtin_amdgcn_mfma_f32_16x16x32_bf16(av, bv, acc[n0], 0, 0, 0);
    }
  }

  // store Whb (bf16), PERMUTED layout: one 16B vector store per reg-row.
#pragma unroll
  for (int reg = 0; reg < 4; ++reg) {
    int r = r0 + lg * 4 + reg;
    if (r < N) {
      short8v pk;
#pragma unroll
      for (int n0 = 0; n0 < 8; ++n0) pk[n0] = (short)f2bf(acc[n0][reg]);
      *(short8v*)(Whb + (size_t)r * 128 + lm * 8) = pk;
    }
  }

  // fused alpha: reduce over the 16 lm lanes
#pragma unroll
  for (int reg = 0; reg < 4; ++reg) {
    float ps = 0.f, pd = 0.f;
#pragma unroll
    for (int n0 = 0; n0 < 8; ++n0) {
      ps += acc[n0][reg] * as_v[n0];
      pd += acc[n0][reg] * ad_v[n0];
    }
#pragma unroll
    for (int off = 1; off < 16; off <<= 1) {
      ps += __shfl_xor(ps, off);
      pd += __shfl_xor(pd, off);
    }
    int r = r0 + lg * 4 + reg;
    if (lm == 0 && r < N) { asrc[r] = ps; adst[r] = pd; }
  }
}

// ---------- K3: phase 1 sort — coarse-bin packed records by col bucket ----------
#define TILE 8192
__global__ __launch_bounds__(1024) void bin_k(const unsigned* __restrict__ packed,
                                              int* __restrict__ bcur,
                                              unsigned* __restrict__ bin_buf, int E) {
  __shared__ int lhist[MAXB];
  __shared__ int lbase[MAXB];
  int tid = (int)threadIdx.x;
  int t0 = blockIdx.x * TILE;

  if (tid < MAXB) lhist[tid] = 0;
  __syncthreads();

  unsigned rec[8];
  int rb[8], rr[8];
#pragma unroll
  for (int k = 0; k < 8; ++k) {
    int i = t0 + tid + k * 1024;
    rb[k] = -1;
    if (i < E) {
      rec[k] = packed[i];
      rb[k] = (int)(rec[k] >> (16 + BSHIFT));
      rr[k] = atomicAdd(&lhist[rb[k]], 1);
    }
  }
  __syncthreads();
  if (tid < MAXB) lbase[tid] = lhist[tid] ? atomicAdd(&bcur[tid], lhist[tid]) : 0;
  __syncthreads();
#pragma unroll
  for (int k = 0; k < 8; ++k) {
    if (rb[k] >= 0) bin_buf[lbase[rb[k]] + rr[k]] = rec[k];
  }
}

// ---------- K4: phase 2 sort — bucket-local col hist+scan -> rowptr + permute ----------
__global__ __launch_bounds__(1024) void perm3_k(const unsigned* __restrict__ bin_buf,
                                                const int* __restrict__ bucket_base,
                                                int* __restrict__ rowptr,
                                                ushort* __restrict__ row_sorted,
                                                int N, int nbuckets) {
  __shared__ int hist[MAXB];
  __shared__ int cur[MAXB];
  __shared__ int wsum[16];
  int b = blockIdx.x;
  int tid = (int)threadIdx.x;
  int c0 = b << BSHIFT;
  int ncol = min(MAXB, N - c0);
  int e0 = bucket_base[b], e1 = bucket_base[b + 1];

  if (tid < MAXB) hist[tid] = 0;
  __syncthreads();
  for (int i = e0 + tid; i < e1; i += 1024) {
    int cl = (int)(bin_buf[i] >> 16) - c0;
    if ((unsigned)cl < (unsigned)MAXB) atomicAdd(&hist[cl], 1);  // defensive bound
  }
  __syncthreads();

  int lane = tid & 63, wid = tid >> 6;
  int v = (tid < MAXB) ? hist[tid] : 0;
  int x = v;
#pragma unroll
  for (int off = 1; off < 64; off <<= 1) {
    int t = __shfl_up(x, off);
    if (lane >= off) x += t;
  }
  if (lane == 63) wsum[wid] = x;
  __syncthreads();
  if (tid < MAXB) {
    int woff = 0;
    for (int w = 0; w < wid; ++w) woff += wsum[w];
    int excl = woff + x - v;
    cur[tid] = e0 + excl;
    if (tid < ncol) rowptr[c0 + tid] = e0 + excl;
  }
  if (b == nbuckets - 1 && tid == 0) rowptr[N] = e1;
  __syncthreads();

  for (int i = e0 + tid; i < e1; i += 1024) {
    unsigned rec = bin_buf[i];
    int cl = (int)(rec >> 16) - c0;
    if ((unsigned)cl < (unsigned)MAXB) {
      int p = atomicAdd(&cur[cl], 1);
      row_sorted[p] = (ushort)(rec & 0xffffu);
    }
  }
}

// ---------- K5: fused softmax + aggregation + ELU (one wave per node, no LDS) ----------
// Whb rows are PERMUTED (slot s = lm*8+n0 -> true col n0*16+lm). Lane j's u32 holds
// slots {2j, 2j+1} -> true cols c0 = 32*(j&3) + (j>>2) and c0+16.
__global__ __launch_bounds__(256) void softagg_k(const int* __restrict__ rowptr,
                                                 const ushort* __restrict__ row_sorted,
                                                 const float* __restrict__ asrc,
                                                 const float* __restrict__ adst,
                                                 const ushort* __restrict__ Whb,
                                                 float* __restrict__ out, int N) {
  int node = blockIdx.x * 4 + ((int)threadIdx.x >> 6);
  if (node >= N) return;
  int lane = (int)threadIdx.x & 63;
  int beg = rowptr[node], end = rowptr[node + 1];
  int deg = end - beg;
  float adc = adst[node];
  float ax = 0.f, ay = 0.f;

  if (deg <= 64) {
    int r = 0;
    float v = NEG_BIG;
    if (lane < deg) {
      r = row_sorted[beg + lane];
      v = asrc[r] + adc;
      v = (v >= 0.f) ? v : 0.2f * v;
    }
    float m = v;
#pragma unroll
    for (int off = 32; off > 0; off >>= 1) m = fmaxf(m, __shfl_xor(m, off));
    float e = (lane < deg) ? __expf(v - m) : 0.f;
    float s = e;
#pragma unroll
    for (int off = 32; off > 0; off >>= 1) s += __shfl_xor(s, off);
    float w = e / (s + 1e-16f);

    int j = 0;
    for (; j + 7 < deg; j += 8) {
      float wv[8];
      int rv[8];
#pragma unroll
      for (int q = 0; q < 8; ++q) { wv[q] = __shfl(w, j + q); rv[q] = __shfl(r, j + q); }
      unsigned u[8];
#pragma unroll
      for (int q = 0; q < 8; ++q) u[q] = ((const unsigned*)(Whb + (size_t)rv[q] * 128))[lane];
#pragma unroll
      for (int q = 0; q < 8; ++q) { ax += wv[q] * bf_lo(u[q]); ay += wv[q] * bf_hi(u[q]); }
    }
    for (; j < deg; ++j) {
      float wj = __shfl(w, j);
      int rj = __shfl(r, j);
      unsigned u = ((const unsigned*)(Whb + (size_t)rj * 128))[lane];
      ax += wj * bf_lo(u); ay += wj * bf_hi(u);
    }
  } else {
    float m = NEG_BIG, s = 0.f;
    for (int i = beg + lane; i < end; i += 64) {
      float v = asrc[row_sorted[i]] + adc;
      v = (v >= 0.f) ? v : 0.2f * v;
      if (v > m) { s = s * __expf(m - v) + 1.f; m = v; }
      else       { s += __expf(v - m); }
    }
#pragma unroll
    for (int off = 32; off > 0; off >>= 1) {
      float mo = __shfl_xor(m, off);
      float so = __shfl_xor(s, off);
      float M = fmaxf(m, mo);
      s = s * __expf(m - M) + so * __expf(mo - M);
      m = M;
    }
    float inv = 1.f / (s + 1e-16f);
    for (int i = beg; i < end; ++i) {
      int rj = row_sorted[i];
      float v = asrc[rj] + adc;
      v = (v >= 0.f) ? v : 0.2f * v;
      float wj = __expf(v - m) * inv;
      unsigned u = ((const unsigned*)(Whb + (size_t)rj * 128))[lane];
      ax += wj * bf_lo(u); ay += wj * bf_hi(u);
    }
  }

  ax = ax > 0.f ? ax : expm1f(ax);
  ay = ay > 0.f ? ay : expm1f(ay);
  int c0 = ((lane & 3) << 5) + (lane >> 2);
  float* orow = out + (size_t)node * 128;
  orow[c0] = ax;
  orow[c0 + 16] = ay;
}

extern "C" void kernel_launch(void* const* d_in, const int* in_sizes, int n_in,
                              void* d_out, int out_size, void* d_ws, size_t ws_size,
                              hipStream_t stream) {
  const float* h = (const float*)d_in[0];
  const void* ei = d_in[1];
  const float* W = (const float*)d_in[2];
  const float* a = (const float*)d_in[3];
  int N = in_sizes[0] / 128;
  int E = in_sizes[1] / 2;
  float* out = (float*)d_out;

  // workspace layout:
  // Whb[N*128 u16] | asrc[N] f32 | adst[N] f32 | bucket_count[256] | done[1]+pad |
  // bcur[256] | bucket_base[257]+pad | rowptr[N+1] | bin_buf[E] u32 | packed[E] u32 |
  // row_sorted[E] u16 | Wbf[16384] u16
  ushort* Whb = (ushort*)d_ws;
  float* asrc = (float*)(Whb + (size_t)N * 128);
  float* adst = asrc + N;
  int* bucket_count = (int*)(adst + N);
  int* done = bucket_count + MAXB;
  int* bcur = done + 4;
  int* bucket_base = bcur + MAXB;
  int* rowptr = bucket_base + MAXB + 4;
  unsigned* bin_buf = (unsigned*)(rowptr + N + 1);
  unsigned* packed = bin_buf + E;
  ushort* row_sorted = (ushort*)(packed + E);
  ushort* Wbf = row_sorted + E;

  int nbuckets = (N + MAXB - 1) >> BSHIFT;     // 196
  const int HBLOCKS = 256;
  int gblocks = (N + 63) / 64;                 // 782

  wprep_k<<<64, 256, 0, stream>>>(W, Wbf, bucket_count, done);
  hist_gemm_k<<<HBLOCKS + gblocks, 256, 0, stream>>>(
      ei, E, packed, bucket_count, done, bcur, bucket_base, HBLOCKS,
      h, Wbf, a, Whb, asrc, adst, N);
  bin_k<<<(E + TILE - 1) / TILE, 1024, 0, stream>>>(packed, bcur, bin_buf, E);
  perm3_k<<<nbuckets, 1024, 0, stream>>>(bin_buf, bucket_base, rowptr, row_sorted, N, nbuckets);
  softagg_k<<<(N + 3) / 4, 256, 0, stream>>>(rowptr, row_sorted, asrc, adst, Whb, out, N);
}

// Round 18
// 85.528 us; speedup vs baseline: 1.1715x; 1.0089x over previous
//
#include <hip/hip_runtime.h>
#include <math.h>

#define NEG_BIG -1.0e30f
#define BSHIFT 8                 // bucket = 256 target-node ids
#define MAXB 256

typedef __attribute__((ext_vector_type(8))) short short8v;   // 8 bf16
typedef __attribute__((ext_vector_type(4))) float f32x4;

__device__ __forceinline__ ushort f2bf(float f) {
  unsigned u = __float_as_uint(f);
  unsigned r = (u + 0x7fffu + ((u >> 16) & 1u)) >> 16;  // round-to-nearest-even
  return (ushort)r;
}
__device__ __forceinline__ float bf_lo(unsigned u) { return __uint_as_float(u << 16); }
__device__ __forceinline__ float bf_hi(unsigned u) { return __uint_as_float(u & 0xffff0000u); }

// ---------- K1: W pack (bf16 MFMA B-fragment order) + zero bucket_count/done ----------
__global__ void wprep_k(const float* __restrict__ W, ushort* __restrict__ Wbf,
                        int* __restrict__ bucket_count, int* __restrict__ done) {
  int j = blockIdx.x * blockDim.x + threadIdx.x;
  if (j < MAXB) bucket_count[j] = 0;
  if (j == 0) *done = 0;
  if (j >= 128 * 128) return;
  int i = j & 7;
  int l = (j >> 3) & 63;
  int n0 = (j >> 9) & 7;
  int kk = j >> 12;
  int k = kk * 32 + ((l >> 4) & 3) * 8 + i;
  int n = n0 * 16 + (l & 15);
  Wbf[j] = f2bf(W[k * 128 + n]);
}

// ---------- K2: fused histB (blocks 0..hblocks-1) ∥ gemm (blocks hblocks..) ----------
// histB: convert + pack (col<<16)|row + bucket histogram; last histB block scans.
// gemm: Wh = h @ W via MFMA bf16, B-fragments LDS-staged -> permuted Whb + fused alpha.
// NOTE: requires N < 65536; N = 50000 here.
__global__ __launch_bounds__(256) void hist_gemm_k(
    const void* __restrict__ ei, int E,
    unsigned* __restrict__ packed, int* __restrict__ bucket_count,
    int* __restrict__ done, int* __restrict__ bcur, int* __restrict__ bucket_base,
    int hblocks,
    const float* __restrict__ h, const ushort* __restrict__ Wbf,
    const float* __restrict__ a, ushort* __restrict__ Whb,
    float* __restrict__ asrc, float* __restrict__ adst, int N) {
  __shared__ ushort Bs[16384];   // 32 KB: whole Wbf, staged once per gemm block
  __shared__ int lh[MAXB];
  __shared__ int wsum[4];
  __shared__ int last;
  int tid = (int)threadIdx.x;

  if ((int)blockIdx.x < hblocks) {
    // ================= histB body (R13-proven) =================
    lh[tid] = 0;
    __syncthreads();

    const int* p32 = (const int*)ei;
    bool is64 = true;
#pragma unroll
    for (int i = 0; i < 32; ++i) is64 = is64 && (p32[2 * i + 1] == 0);
    const long long* p64 = (const long long*)ei;
    int stride = hblocks * 256;
    for (int e = blockIdx.x * 256 + tid; e < E; e += stride) {
      int r, c;
      if (is64) { r = (int)p64[e]; c = (int)p64[E + e]; }
      else      { r = p32[e];      c = p32[E + e]; }
      packed[e] = ((unsigned)c << 16) | (unsigned)r;
      atomicAdd(&lh[c >> BSHIFT], 1);
    }
    __syncthreads();
    if (lh[tid]) atomicAdd(&bucket_count[tid], lh[tid]);
    __syncthreads();               // all of this block's adds issued & drained...
    if (tid == 0) {
      __threadfence();             // ...and device-visible before signaling
      int old = atomicAdd(done, 1);
      last = (old == hblocks - 1);
    }
    __syncthreads();
    if (!last) return;
    __threadfence();               // acquire

    int lane = tid & 63, wid = tid >> 6;
    int v = atomicAdd(&bucket_count[tid], 0);
    int x = v;
#pragma unroll
    for (int off = 1; off < 64; off <<= 1) {
      int t = __shfl_up(x, off);
      if (lane >= off) x += t;
    }
    if (lane == 63) wsum[wid] = x;
    __syncthreads();
    int woff = 0;
    for (int w = 0; w < wid; ++w) woff += wsum[w];
    int excl = woff + x - v;
    bcur[tid] = excl;
    bucket_base[tid] = excl;
    if (tid == 255) bucket_base[256] = excl + v;
    return;
  }

  // ================= gemm body =================
  // k-map (applied identically to A and B -> result layout-invariant): k = kk*32+lg*8+i
  // Whb PERMUTED row layout: Whb[r][lm*8 + n0] holds true col (n0*16 + lm).

  // stage Wbf -> LDS (coalesced 16B chunks; L2-hot source)
  {
    const ulong2* src = (const ulong2*)Wbf;
    ulong2* dst = (ulong2*)Bs;
#pragma unroll
    for (int i = 0; i < 8; ++i) dst[i * 256 + tid] = src[i * 256 + tid];
  }
  __syncthreads();

  int gb = (int)blockIdx.x - hblocks;
  int w = tid >> 6;
  int l = tid & 63;
  int lg = l >> 4;
  int lm = l & 15;
  int r0 = gb * 64 + 16 * w;
  const short8v* Bs8 = (const short8v*)Bs;

  float as_v[8], ad_v[8];
#pragma unroll
  for (int n0 = 0; n0 < 8; ++n0) {
    as_v[n0] = a[n0 * 16 + lm];
    ad_v[n0] = a[128 + n0 * 16 + lm];
  }

  f32x4 acc[8];
#pragma unroll
  for (int n0 = 0; n0 < 8; ++n0) acc[n0] = (f32x4){0.f, 0.f, 0.f, 0.f};

  int arow = r0 + lm;
  const float* hrow = h + (size_t)arow * 128;
  bool rok = (arow < N);

#pragma unroll
  for (int kk = 0; kk < 4; ++kk) {
    short8v av;
    if (rok) {
      const float4* hp = (const float4*)(hrow + kk * 32 + lg * 8);
      float4 x0 = hp[0], x1 = hp[1];
      av[0] = (short)f2bf(x0.x); av[1] = (short)f2bf(x0.y);
      av[2] = (short)f2bf(x0.z); av[3] = (short)f2bf(x0.w);
      av[4] = (short)f2bf(x1.x); av[5] = (short)f2bf(x1.y);
      av[6] = (short)f2bf(x1.z); av[7] = (short)f2bf(x1.w);
    } else {
      av = (short8v){0, 0, 0, 0, 0, 0, 0, 0};
    }
#pragma unroll
    for (int n0 = 0; n0 < 8; ++n0) {
      short8v bv = Bs8[(kk * 8 + n0) * 64 + l];
      acc[n0] = __builtin_amdgcn_mfma_f32_16x16x32_bf16(av, bv, acc[n0], 0, 0, 0);
    }
  }

  // store Whb (bf16), PERMUTED layout: one 16B vector store per reg-row.
#pragma unroll
  for (int reg = 0; reg < 4; ++reg) {
    int r = r0 + lg * 4 + reg;
    if (r < N) {
      short8v pk;
#pragma unroll
      for (int n0 = 0; n0 < 8; ++n0) pk[n0] = (short)f2bf(acc[n0][reg]);
      *(short8v*)(Whb + (size_t)r * 128 + lm * 8) = pk;
    }
  }

  // fused alpha: reduce over the 16 lm lanes
#pragma unroll
  for (int reg = 0; reg < 4; ++reg) {
    float ps = 0.f, pd = 0.f;
#pragma unroll
    for (int n0 = 0; n0 < 8; ++n0) {
      ps += acc[n0][reg] * as_v[n0];
      pd += acc[n0][reg] * ad_v[n0];
    }
#pragma unroll
    for (int off = 1; off < 16; off <<= 1) {
      ps += __shfl_xor(ps, off);
      pd += __shfl_xor(pd, off);
    }
    int r = r0 + lg * 4 + reg;
    if (lm == 0 && r < N) { asrc[r] = ps; adst[r] = pd; }
  }
}

// ---------- K3: phase 1 sort — coarse-bin packed records by col bucket ----------
#define TILE 8192
__global__ __launch_bounds__(1024) void bin_k(const unsigned* __restrict__ packed,
                                              int* __restrict__ bcur,
                                              unsigned* __restrict__ bin_buf, int E) {
  __shared__ int lhist[MAXB];
  __shared__ int lbase[MAXB];
  int tid = (int)threadIdx.x;
  int t0 = blockIdx.x * TILE;

  if (tid < MAXB) lhist[tid] = 0;
  __syncthreads();

  unsigned rec[8];
  int rb[8], rr[8];
#pragma unroll
  for (int k = 0; k < 8; ++k) {
    int i = t0 + tid + k * 1024;
    rb[k] = -1;
    if (i < E) {
      rec[k] = packed[i];
      rb[k] = (int)(rec[k] >> (16 + BSHIFT));
      rr[k] = atomicAdd(&lhist[rb[k]], 1);
    }
  }
  __syncthreads();
  if (tid < MAXB) lbase[tid] = lhist[tid] ? atomicAdd(&bcur[tid], lhist[tid]) : 0;
  __syncthreads();
#pragma unroll
  for (int k = 0; k < 8; ++k) {
    if (rb[k] >= 0) bin_buf[lbase[rb[k]] + rr[k]] = rec[k];
  }
}

// ---------- K4: phase 2 sort — bucket-local col hist+scan -> rowptr + permute ----------
__global__ __launch_bounds__(1024) void perm3_k(const unsigned* __restrict__ bin_buf,
                                                const int* __restrict__ bucket_base,
                                                int* __restrict__ rowptr,
                                                ushort* __restrict__ row_sorted,
                                                int N, int nbuckets) {
  __shared__ int hist[MAXB];
  __shared__ int cur[MAXB];
  __shared__ int wsum[16];
  int b = blockIdx.x;
  int tid = (int)threadIdx.x;
  int c0 = b << BSHIFT;
  int ncol = min(MAXB, N - c0);
  int e0 = bucket_base[b], e1 = bucket_base[b + 1];

  if (tid < MAXB) hist[tid] = 0;
  __syncthreads();
  for (int i = e0 + tid; i < e1; i += 1024) {
    int cl = (int)(bin_buf[i] >> 16) - c0;
    if ((unsigned)cl < (unsigned)MAXB) atomicAdd(&hist[cl], 1);  // defensive bound
  }
  __syncthreads();

  int lane = tid & 63, wid = tid >> 6;
  int v = (tid < MAXB) ? hist[tid] : 0;
  int x = v;
#pragma unroll
  for (int off = 1; off < 64; off <<= 1) {
    int t = __shfl_up(x, off);
    if (lane >= off) x += t;
  }
  if (lane == 63) wsum[wid] = x;
  __syncthreads();
  if (tid < MAXB) {
    int woff = 0;
    for (int w = 0; w < wid; ++w) woff += wsum[w];
    int excl = woff + x - v;
    cur[tid] = e0 + excl;
    if (tid < ncol) rowptr[c0 + tid] = e0 + excl;
  }
  if (b == nbuckets - 1 && tid == 0) rowptr[N] = e1;
  __syncthreads();

  for (int i = e0 + tid; i < e1; i += 1024) {
    unsigned rec = bin_buf[i];
    int cl = (int)(rec >> 16) - c0;
    if ((unsigned)cl < (unsigned)MAXB) {
      int p = atomicAdd(&cur[cl], 1);
      row_sorted[p] = (ushort)(rec & 0xffffu);
    }
  }
}

// ---------- K5: fused softmax + aggregation + ELU (one wave per node, no LDS) ----------
// Whb rows are PERMUTED (slot s = lm*8+n0 -> true col n0*16+lm); true col(s) = (s&7)*16 + (s>>3).
// Fast path gathers TWO edges per u64 load: lanes 0-31 = even edge, lanes 32-63 = odd edge;
// lane jj holds slots 4jj..4jj+3; cross-add halves via shfl_xor(32) at the end.
// NOTE: all __shfl calls are CONVERGENT (executed by all 64 lanes) — ds_bpermute
// returns 0 from EXEC-inactive source lanes, so a shfl under a divergent ternary
// silently drops data (R17 bug: odd-deg >= 33 nodes lost their last edge).
__global__ __launch_bounds__(256) void softagg_k(const int* __restrict__ rowptr,
                                                 const ushort* __restrict__ row_sorted,
                                                 const float* __restrict__ asrc,
                                                 const float* __restrict__ adst,
                                                 const ushort* __restrict__ Whb,
                                                 float* __restrict__ out, int N) {
  int node = blockIdx.x * 4 + ((int)threadIdx.x >> 6);
  if (node >= N) return;
  int lane = (int)threadIdx.x & 63;
  int beg = rowptr[node], end = rowptr[node + 1];
  int deg = end - beg;
  float adc = adst[node];
  float* orow = out + (size_t)node * 128;

  if (deg <= 64) {
    // softmax: one edge per lane, entirely in registers
    int r = 0;
    float v = NEG_BIG;
    if (lane < deg) {
      r = row_sorted[beg + lane];
      v = asrc[r] + adc;
      v = (v >= 0.f) ? v : 0.2f * v;
    }
    float m = v;
#pragma unroll
    for (int off = 32; off > 0; off >>= 1) m = fmaxf(m, __shfl_xor(m, off));
    float e = (lane < deg) ? __expf(v - m) : 0.f;
    float s = e;
#pragma unroll
    for (int off = 32; off > 0; off >>= 1) s += __shfl_xor(s, off);
    float w = e / (s + 1e-16f);

    // pair-gather: lanes split into two halves; each pair = one u64 load per lane
    int half = lane >> 5;        // 0: even edge of pair, 1: odd edge
    int jj = lane & 31;          // u64 slot within row
    float a0 = 0.f, a1 = 0.f, a2 = 0.f, a3 = 0.f;
    int npair = (deg + 1) >> 1;
    int p = 0;

#define PAIR_STEP(q, pbase)                                                        \
    {                                                                              \
      int idx = 2 * ((pbase) + (q)) + half;                                        \
      int idxc = min(idx, deg - 1);                                                \
      float wq = __shfl(w, idxc);   /* convergent shfl, then select */             \
      wv[q] = (idx < deg) ? wq : 0.f;                                              \
      rv[q] = __shfl(r, idxc);                                                     \
    }
#define PAIR_ACC(q)                                                                \
    {                                                                              \
      unsigned ulo = (unsigned)(uv[q] & 0xffffffffull);                            \
      unsigned uhi = (unsigned)(uv[q] >> 32);                                      \
      a0 += wv[q] * bf_lo(ulo); a1 += wv[q] * bf_hi(ulo);                          \
      a2 += wv[q] * bf_lo(uhi); a3 += wv[q] * bf_hi(uhi);                          \
    }

    for (; p + 8 <= npair; p += 8) {
      float wv[8]; int rv[8]; unsigned long long uv[8];
#pragma unroll
      for (int q = 0; q < 8; ++q) PAIR_STEP(q, p)
#pragma unroll
      for (int q = 0; q < 8; ++q) uv[q] = ((const unsigned long long*)(Whb + (size_t)rv[q] * 128))[jj];
#pragma unroll
      for (int q = 0; q < 8; ++q) PAIR_ACC(q)
    }
    if (p + 4 <= npair) {
      float wv[4]; int rv[4]; unsigned long long uv[4];
#pragma unroll
      for (int q = 0; q < 4; ++q) PAIR_STEP(q, p)
#pragma unroll
      for (int q = 0; q < 4; ++q) uv[q] = ((const unsigned long long*)(Whb + (size_t)rv[q] * 128))[jj];
#pragma unroll
      for (int q = 0; q < 4; ++q) PAIR_ACC(q)
      p += 4;
    }
    for (; p < npair; ++p) {
      float wv[1]; int rv[1]; unsigned long long uv[1];
      PAIR_STEP(0, p)
      uv[0] = ((const unsigned long long*)(Whb + (size_t)rv[0] * 128))[jj];
      PAIR_ACC(0)
    }
#undef PAIR_STEP
#undef PAIR_ACC

    // merge the two half-wave partial sums
    a0 += __shfl_xor(a0, 32);
    a1 += __shfl_xor(a1, 32);
    a2 += __shfl_xor(a2, 32);
    a3 += __shfl_xor(a3, 32);

    if (half == 0) {
      // lane jj holds slots 4jj..4jj+3; ELU + un-permute store
      float vals[4] = {a0, a1, a2, a3};
#pragma unroll
      for (int t = 0; t < 4; ++t) {
        int sslot = 4 * jj + t;
        float x = vals[t];
        x = x > 0.f ? x : expm1f(x);
        orow[(sslot & 7) * 16 + (sslot >> 3)] = x;
      }
    }
  } else {
    // slow path (deg > 64): online softmax + recompute weights (u32 over 64 lanes)
    float ax = 0.f, ay = 0.f;
    float m = NEG_BIG, s = 0.f;
    for (int i = beg + lane; i < end; i += 64) {
      float v = asrc[row_sorted[i]] + adc;
      v = (v >= 0.f) ? v : 0.2f * v;
      if (v > m) { s = s * __expf(m - v) + 1.f; m = v; }
      else       { s += __expf(v - m); }
    }
#pragma unroll
    for (int off = 32; off > 0; off >>= 1) {
      float mo = __shfl_xor(m, off);
      float so = __shfl_xor(s, off);
      float M = fmaxf(m, mo);
      s = s * __expf(m - M) + so * __expf(mo - M);
      m = M;
    }
    float inv = 1.f / (s + 1e-16f);
    for (int i = beg; i < end; ++i) {
      int rj = row_sorted[i];
      float v = asrc[rj] + adc;
      v = (v >= 0.f) ? v : 0.2f * v;
      float wj = __expf(v - m) * inv;
      unsigned u = ((const unsigned*)(Whb + (size_t)rj * 128))[lane];
      ax += wj * bf_lo(u); ay += wj * bf_hi(u);
    }
    ax = ax > 0.f ? ax : expm1f(ax);
    ay = ay > 0.f ? ay : expm1f(ay);
    int c0 = ((lane & 3) << 5) + (lane >> 2);
    orow[c0] = ax;
    orow[c0 + 16] = ay;
  }
}

extern "C" void kernel_launch(void* const* d_in, const int* in_sizes, int n_in,
                              void* d_out, int out_size, void* d_ws, size_t ws_size,
                              hipStream_t stream) {
  const float* h = (const float*)d_in[0];
  const void* ei = d_in[1];
  const float* W = (const float*)d_in[2];
  const float* a = (const float*)d_in[3];
  int N = in_sizes[0] / 128;
  int E = in_sizes[1] / 2;
  float* out = (float*)d_out;

  // workspace layout:
  // Whb[N*128 u16] | asrc[N] f32 | adst[N] f32 | bucket_count[256] | done[1]+pad |
  // bcur[256] | bucket_base[257]+pad | rowptr[N+1] | bin_buf[E] u32 | packed[E] u32 |
  // row_sorted[E] u16 | Wbf[16384] u16
  ushort* Whb = (ushort*)d_ws;
  float* asrc = (float*)(Whb + (size_t)N * 128);
  float* adst = asrc + N;
  int* bucket_count = (int*)(adst + N);
  int* done = bucket_count + MAXB;
  int* bcur = done + 4;
  int* bucket_base = bcur + MAXB;
  int* rowptr = bucket_base + MAXB + 4;
  unsigned* bin_buf = (unsigned*)(rowptr + N + 1);
  unsigned* packed = bin_buf + E;
  ushort* row_sorted = (ushort*)(packed + E);
  ushort* Wbf = row_sorted + E;

  int nbuckets = (N + MAXB - 1) >> BSHIFT;     // 196
  const int HBLOCKS = 256;
  int gblocks = (N + 63) / 64;                 // 782

  wprep_k<<<64, 256, 0, stream>>>(W, Wbf, bucket_count, done);
  hist_gemm_k<<<HBLOCKS + gblocks, 256, 0, stream>>>(
      ei, E, packed, bucket_count, done, bcur, bucket_base, HBLOCKS,
      h, Wbf, a, Whb, asrc, adst, N);
  bin_k<<<(E + TILE - 1) / TILE, 1024, 0, stream>>>(packed, bcur, bin_buf, E);
  perm3_k<<<nbuckets, 1024, 0, stream>>>(bin_buf, bucket_base, rowptr, row_sorted, N, nbuckets);
  softagg_k<<<(N + 3) / 4, 256, 0, stream>>>(rowptr, row_sorted, asrc, adst, Whb, out, N);
}